// Round 6
// baseline (361.398 us; speedup 1.0000x reference)
//
#include <hip/hip_runtime.h>
#include <cstddef>

#define D 128
#define BW_LOG 11
#define BW 2048            // nodes per bucket (NB = ceil(n/BW) <= 256 required)
#define CHUNK 8192         // edges per bscatter/bhist block
#define GP 136             // LDS pitch (ushorts) for W tiles: 272B, 16B-aligned, 2-way banks
typedef unsigned int uint;
typedef unsigned short ushort;

typedef __attribute__((ext_vector_type(8))) short bf16x8;
typedef __attribute__((ext_vector_type(4))) float f32x4;

// ---- bf16 helpers (RNE) ----
static __device__ __forceinline__ uint bf16r(float x) {
  uint u = __float_as_uint(x);
  return (u + 0x7fffu + ((u >> 16) & 1u)) >> 16;
}
static __device__ __forceinline__ uint pack2(float a, float b) {
  return bf16r(a) | (bf16r(b) << 16);
}
static __device__ __forceinline__ void acc_bf16x8(const uint4 v, float* a) {
  a[0] += __uint_as_float(v.x << 16);
  a[1] += __uint_as_float(v.x & 0xffff0000u);
  a[2] += __uint_as_float(v.y << 16);
  a[3] += __uint_as_float(v.y & 0xffff0000u);
  a[4] += __uint_as_float(v.z << 16);
  a[5] += __uint_as_float(v.z & 0xffff0000u);
  a[6] += __uint_as_float(v.w << 16);
  a[7] += __uint_as_float(v.w & 0xffff0000u);
}

// ================= bucketed CSR build =================
__global__ void k_bzero(int* __restrict__ bcnt, int nb) {
  int t = threadIdx.x;
  if (t < nb) bcnt[t] = 0;
}

__global__ __launch_bounds__(512)
void k_bhist(const int* __restrict__ dstA, int* __restrict__ bcnt, int e, int nb) {
  __shared__ int h[256];
  int t = threadIdx.x;
  if (t < nb) h[t] = 0;
  __syncthreads();
  int base = blockIdx.x * CHUNK;
  int m = min(CHUNK, e - base);
  for (int i = t; i < m; i += 512) atomicAdd(&h[dstA[base + i] >> BW_LOG], 1);
  __syncthreads();
  if (t < nb && h[t]) atomicAdd(&bcnt[t], h[t]);
}

__global__ void k_bscan(const int* __restrict__ bcnt, int* __restrict__ bbase,
                        int* __restrict__ cursor, int* __restrict__ off,
                        int nb, int n, int e) {
  __shared__ int s[256];
  int t = threadIdx.x;
  int v = (t < nb) ? bcnt[t] : 0;
  s[t] = v;
  __syncthreads();
  for (int d = 1; d < 256; d <<= 1) {
    int x = (t >= d) ? s[t - d] : 0;
    __syncthreads();
    s[t] += x;
    __syncthreads();
  }
  if (t < nb) {
    int b = s[t] - v;
    bbase[t] = b;
    cursor[t] = b;
  }
  if (t == 0) {
    bbase[nb] = e;
    off[n] = e;
  }
}

__global__ __launch_bounds__(512)
void k_bscatter(const int* __restrict__ ei, int* __restrict__ cursor,
                int* __restrict__ pk, int e, int nb) {
  __shared__ int h[256], lbase[256], gpos[256], lcur[256], s2[256];
  __shared__ int staged[CHUNK];
  int t = threadIdx.x;
  if (t < nb) h[t] = 0;
  __syncthreads();
  int base = blockIdx.x * CHUNK;
  int m = min(CHUNK, e - base);
  int sv[16], dv[16];
#pragma unroll
  for (int k = 0; k < 16; ++k) {
    int i = t + k * 512;
    sv[k] = 0; dv[k] = 0;
    if (i < m) {
      sv[k] = ei[base + i];
      dv[k] = ei[e + base + i];
      atomicAdd(&h[dv[k] >> BW_LOG], 1);
    }
  }
  __syncthreads();
  if (t < 256) s2[t] = (t < nb) ? h[t] : 0;
  __syncthreads();
  for (int d = 1; d < 256; d <<= 1) {
    int x = 0;
    if (t < 256 && t >= d) x = s2[t - d];
    __syncthreads();
    if (t < 256) s2[t] += x;
    __syncthreads();
  }
  if (t < nb) {
    lbase[t] = s2[t] - h[t];
    lcur[t] = s2[t] - h[t];
    gpos[t] = h[t] ? atomicAdd(&cursor[t], h[t]) : 0;
  }
  __syncthreads();
#pragma unroll
  for (int k = 0; k < 16; ++k) {
    int i = t + k * 512;
    if (i < m) {
      int b = dv[k] >> BW_LOG;
      int p = atomicAdd(&lcur[b], 1);
      staged[p] = sv[k] | ((dv[k] & (BW - 1)) << 17);
    }
  }
  __syncthreads();
  for (int b = 0; b < nb; ++b) {
    int cnt = h[b], lb = lbase[b], gp = gpos[b];
    for (int i = t; i < cnt; i += 512) pk[gp + i] = staged[lb + i];
  }
}

__global__ __launch_bounds__(1024)
void k_bfinal(const int* __restrict__ bbase, const int* __restrict__ pk,
              int* __restrict__ off, float* __restrict__ dinv,
              int* __restrict__ csr, int n, int nb) {
  __shared__ int sc[BW];
  __shared__ int lcur[BW];
  const int b = blockIdx.x;
  const int t = threadIdx.x;
  const int e0 = bbase[b], e1 = bbase[b + 1];
  const int node0 = b << BW_LOG;
  sc[t] = 0; sc[t + 1024] = 0;
  lcur[t] = 0; lcur[t + 1024] = 0;
  __syncthreads();
  for (int i = e0 + t; i < e1; i += 1024) atomicAdd(&sc[(pk[i] >> 17) & (BW - 1)], 1);
  __syncthreads();
  int c0 = sc[t], c1 = sc[t + 1024];
  for (int d = 1; d < BW; d <<= 1) {
    int v0 = (t >= d) ? sc[t - d] : 0;
    int v1 = (t + 1024 >= d) ? sc[t + 1024 - d] : 0;
    __syncthreads();
    sc[t] += v0; sc[t + 1024] += v1;
    __syncthreads();
  }
  int ex0 = sc[t] - c0, ex1 = sc[t + 1024] - c1;
  int na = node0 + t, nbn = node0 + t + 1024;
  if (na < n)  { off[na]  = e0 + ex0; dinv[na]  = rsqrtf((float)c0 + 1.0f); }
  if (nbn < n) { off[nbn] = e0 + ex1; dinv[nbn] = rsqrtf((float)c1 + 1.0f); }
  __syncthreads();
  sc[t] = ex0; sc[t + 1024] = ex1;
  __syncthreads();
  for (int i = e0 + t; i < e1; i += 1024) {
    int v = pk[i];
    int dl = (v >> 17) & (BW - 1);
    int p = atomicAdd(&lcur[dl], 1);
    csr[e0 + sc[dl] + p] = v & 0x1FFFF;
  }
}

// ================= MFMA GEMM (f32 input, split hi/lo A): layer 0 =================
// 8 waves/block (512 thr), Wh/Wl in LDS (69.6KB) -> 2 blocks/CU = 4 waves/SIMD.
__global__ __launch_bounds__(512)
void k_mgemm_f32(const float* __restrict__ X, const float* __restrict__ W,
                 const float* __restrict__ dinv, ushort* __restrict__ Asb,
                 int n, int nstrips) {
  __shared__ __align__(16) ushort Wh[128 * GP];
  __shared__ __align__(16) ushort Wl[128 * GP];
  const int tid = threadIdx.x;

  for (int i = tid; i < 4096; i += 512) {
    int nn = i & 127;
    int k0 = (i >> 7) * 4;
    union { ushort4 v; ushort a[4]; } h, l;
#pragma unroll
    for (int r = 0; r < 4; ++r) {
      float w = W[(size_t)(k0 + r) * D + nn];
      uint hb = bf16r(w);
      float hf = __uint_as_float(hb << 16);
      h.a[r] = (ushort)hb;
      l.a[r] = (ushort)bf16r(w - hf);
    }
    *(ushort4*)(&Wh[nn * GP + k0]) = h.v;
    *(ushort4*)(&Wl[nn * GP + k0]) = l.v;
  }
  __syncthreads();

  const int wv = tid >> 6;
  const int l = tid & 63;
  const int lr = l & 15;
  const int lk = (l >> 4) * 8;

  for (int strip = blockIdx.x * 8 + wv; strip < nstrips; strip += gridDim.x * 8) {
    const int row0 = strip * 16;
    f32x4 acc[8];
#pragma unroll
    for (int t = 0; t < 8; ++t) acc[t] = (f32x4){0.f, 0.f, 0.f, 0.f};

    const int arow = row0 + lr;
    const bool av = (arow < n);
    const float* ap = X + (size_t)arow * D;

#pragma unroll
    for (int ks = 0; ks < 4; ++ks) {
      const int k0 = ks * 32 + lk;
      float a8[8];
      if (av) {
        float4 u0 = *(const float4*)(ap + k0);
        float4 u1 = *(const float4*)(ap + k0 + 4);
        a8[0] = u0.x; a8[1] = u0.y; a8[2] = u0.z; a8[3] = u0.w;
        a8[4] = u1.x; a8[5] = u1.y; a8[6] = u1.z; a8[7] = u1.w;
      } else {
#pragma unroll
        for (int j = 0; j < 8; ++j) a8[j] = 0.f;
      }
      union { bf16x8 v; ushort a[8]; } ah, al;
#pragma unroll
      for (int j = 0; j < 8; ++j) {
        uint hb = bf16r(a8[j]);
        float hf = __uint_as_float(hb << 16);
        ah.a[j] = (ushort)hb;
        al.a[j] = (ushort)bf16r(a8[j] - hf);
      }
#pragma unroll
      for (int nt = 0; nt < 8; ++nt) {
        bf16x8 bh = *(const bf16x8*)(&Wh[(nt * 16 + lr) * GP + k0]);
        bf16x8 bl = *(const bf16x8*)(&Wl[(nt * 16 + lr) * GP + k0]);
        acc[nt] = __builtin_amdgcn_mfma_f32_16x16x32_bf16(ah.v, bh, acc[nt], 0, 0, 0);
        acc[nt] = __builtin_amdgcn_mfma_f32_16x16x32_bf16(al.v, bh, acc[nt], 0, 0, 0);
        acc[nt] = __builtin_amdgcn_mfma_f32_16x16x32_bf16(ah.v, bl, acc[nt], 0, 0, 0);
      }
    }

#pragma unroll
    for (int r = 0; r < 4; ++r) {
      int row = row0 + (l >> 4) * 4 + r;
      if (row < n) {
        float di = dinv[row];
#pragma unroll
        for (int nt = 0; nt < 8; ++nt) {
          Asb[(size_t)row * D + nt * 16 + lr] = (ushort)bf16r(acc[nt][r] * di);
        }
      }
    }
  }
}

// ================= MFMA GEMM (bf16 input, exact A): layer 1 =================
// A is exact bf16 (already relu+bias'd) -> Alo=0 -> 2 MFMA terms, b128 A-frag load.
__global__ __launch_bounds__(512)
void k_mgemm_bf(const ushort* __restrict__ Xb, const float* __restrict__ W,
                const float* __restrict__ dinv, ushort* __restrict__ Asb,
                int n, int nstrips) {
  __shared__ __align__(16) ushort Wh[128 * GP];
  __shared__ __align__(16) ushort Wl[128 * GP];
  const int tid = threadIdx.x;

  for (int i = tid; i < 4096; i += 512) {
    int nn = i & 127;
    int k0 = (i >> 7) * 4;
    union { ushort4 v; ushort a[4]; } h, l;
#pragma unroll
    for (int r = 0; r < 4; ++r) {
      float w = W[(size_t)(k0 + r) * D + nn];
      uint hb = bf16r(w);
      float hf = __uint_as_float(hb << 16);
      h.a[r] = (ushort)hb;
      l.a[r] = (ushort)bf16r(w - hf);
    }
    *(ushort4*)(&Wh[nn * GP + k0]) = h.v;
    *(ushort4*)(&Wl[nn * GP + k0]) = l.v;
  }
  __syncthreads();

  const int wv = tid >> 6;
  const int l = tid & 63;
  const int lr = l & 15;
  const int lk = (l >> 4) * 8;

  for (int strip = blockIdx.x * 8 + wv; strip < nstrips; strip += gridDim.x * 8) {
    const int row0 = strip * 16;
    f32x4 acc[8];
#pragma unroll
    for (int t = 0; t < 8; ++t) acc[t] = (f32x4){0.f, 0.f, 0.f, 0.f};

    const int arow = row0 + lr;
    const bool av = (arow < n);
    const ushort* ap = Xb + (size_t)arow * D;

#pragma unroll
    for (int ks = 0; ks < 4; ++ks) {
      const int k0 = ks * 32 + lk;
      bf16x8 ah;
      if (av) {
        ah = *(const bf16x8*)(ap + k0);
      } else {
        union { bf16x8 v; ushort a[8]; } z;
#pragma unroll
        for (int j = 0; j < 8; ++j) z.a[j] = 0;
        ah = z.v;
      }
#pragma unroll
      for (int nt = 0; nt < 8; ++nt) {
        bf16x8 bh = *(const bf16x8*)(&Wh[(nt * 16 + lr) * GP + k0]);
        bf16x8 bl = *(const bf16x8*)(&Wl[(nt * 16 + lr) * GP + k0]);
        acc[nt] = __builtin_amdgcn_mfma_f32_16x16x32_bf16(ah, bh, acc[nt], 0, 0, 0);
        acc[nt] = __builtin_amdgcn_mfma_f32_16x16x32_bf16(ah, bl, acc[nt], 0, 0, 0);
      }
    }

#pragma unroll
    for (int r = 0; r < 4; ++r) {
      int row = row0 + (l >> 4) * 4 + r;
      if (row < n) {
        float di = dinv[row];
#pragma unroll
        for (int nt = 0; nt < 8; ++nt) {
          Asb[(size_t)row * D + nt * 16 + lr] = (ushort)bf16r(acc[nt][r] * di);
        }
      }
    }
  }
}

// ================= gather aggregate =================
// FUSE_DOT=false: Bb = bf16(relu(acc*di + b0))  (feeds layer-1 GEMM directly)
// FUSE_DOT=true : ss = dinv*(relu(acc*di + b1) . W2)
template <bool FUSE_DOT>
__global__ __launch_bounds__(256)
void k_gather(const int* __restrict__ off, const int* __restrict__ csr,
              const float* __restrict__ dinv, const ushort* __restrict__ Asb,
              ushort* __restrict__ Bb, const float* __restrict__ bias,
              const float* __restrict__ W2, float* __restrict__ ss, int n) {
  const int wid = blockIdx.x * 4 + (threadIdx.x >> 6);
  if (wid >= n) return;
  const int lane = threadIdx.x & 63;
  const int q = lane >> 4;
  const int li = lane & 15;
  const int c = li << 3;

  float a[8];
#pragma unroll
  for (int k = 0; k < 8; ++k) a[k] = 0.f;
  if (q == 0) {
    uint4 sv = *(const uint4*)(Asb + (size_t)wid * D + c);
    acc_bf16x8(sv, a);
  }

  const int o0 = off[wid], o1 = off[wid + 1];
  for (int j0 = o0; j0 < o1; j0 += 64) {
    int sj = 0;
    if (j0 + lane < o1) sj = csr[j0 + lane];
    const int m = min(64, o1 - j0);
    const int nst = (m + 3) >> 2;
#pragma unroll 4
    for (int t = 0; t < nst; ++t) {
      int idx = (t << 2) + q;
      int s = __shfl(sj, idx);
      if (idx < m) {
        uint4 v = *(const uint4*)(Asb + (size_t)s * D + c);
        acc_bf16x8(v, a);
      }
    }
  }

#pragma unroll
  for (int k = 0; k < 8; ++k) {
    a[k] += __shfl_xor(a[k], 16);
    a[k] += __shfl_xor(a[k], 32);
  }

  const float di = dinv[wid];
  float4 bb0 = *(const float4*)(bias + c);
  float4 bb1 = *(const float4*)(bias + c + 4);
  float v0 = fmaxf(a[0] * di + bb0.x, 0.f);
  float v1 = fmaxf(a[1] * di + bb0.y, 0.f);
  float v2 = fmaxf(a[2] * di + bb0.z, 0.f);
  float v3 = fmaxf(a[3] * di + bb0.w, 0.f);
  float v4 = fmaxf(a[4] * di + bb1.x, 0.f);
  float v5 = fmaxf(a[5] * di + bb1.y, 0.f);
  float v6 = fmaxf(a[6] * di + bb1.z, 0.f);
  float v7 = fmaxf(a[7] * di + bb1.w, 0.f);

  if (FUSE_DOT) {
    float4 w0 = *(const float4*)(W2 + c);
    float4 w1 = *(const float4*)(W2 + c + 4);
    float p = v0 * w0.x + v1 * w0.y + v2 * w0.z + v3 * w0.w +
              v4 * w1.x + v5 * w1.y + v6 * w1.z + v7 * w1.w;
    p += __shfl_xor(p, 1);
    p += __shfl_xor(p, 2);
    p += __shfl_xor(p, 4);
    p += __shfl_xor(p, 8);
    if (lane == 0) ss[wid] = p * di;
  } else {
    if (lane < 16) {
      uint4 w;
      w.x = pack2(v0, v1);
      w.y = pack2(v2, v3);
      w.z = pack2(v4, v5);
      w.w = pack2(v6, v7);
      *(uint4*)(Bb + (size_t)wid * D + c) = w;
    }
  }
}

// ================= scalar gather + sigmoid =================
__global__ void k_gather_scalar(const int* __restrict__ off, const int* __restrict__ csr,
                                const float* __restrict__ dinv, const float* __restrict__ ss,
                                const float* __restrict__ b2, float* __restrict__ out, int n) {
  int i = blockIdx.x * 256 + threadIdx.x;
  if (i >= n) return;
  float acc = ss[i];
  int j = off[i], o1 = off[i + 1];
  float a0 = 0.f, a1 = 0.f, a2 = 0.f, a3 = 0.f;
  for (; j + 4 <= o1; j += 4) {
    int s0 = csr[j], s1 = csr[j + 1], s2 = csr[j + 2], s3 = csr[j + 3];
    a0 += ss[s0];
    a1 += ss[s1];
    a2 += ss[s2];
    a3 += ss[s3];
  }
  for (; j < o1; ++j) a0 += ss[csr[j]];
  acc += (a0 + a1) + (a2 + a3);
  float v = acc * dinv[i] + b2[0];
  out[i] = 1.f / (1.f + expf(-v));
}

// ================= launch =================
extern "C" void kernel_launch(void* const* d_in, const int* in_sizes, int n_in,
                              void* d_out, int out_size, void* d_ws, size_t ws_size,
                              hipStream_t stream) {
  const float* x  = (const float*)d_in[0];
  const int*   ei = (const int*)d_in[1];   // int64 in source collapses to int32 (JAX x64 off)
  const float* W0 = (const float*)d_in[2];
  const float* b0 = (const float*)d_in[3];
  const float* W1 = (const float*)d_in[4];
  const float* b1 = (const float*)d_in[5];
  const float* W2 = (const float*)d_in[6];
  const float* b2 = (const float*)d_in[7];
  float* out = (float*)d_out;

  const int n = in_sizes[0] / D;
  const int e = in_sizes[1] / 2;
  const int nb = (n + BW - 1) / BW;                 // buckets (n=100000 -> 49)
  const int nstrips = (n + 15) / 16;
  const size_t np = ((size_t)n + 256) / 256 * 256;  // holds n+1, 256-aligned

  float* ws = (float*)d_ws;
  int*    off    = (int*)ws;                         // np
  float*  dinv   = ws + np;                          // np
  float*  ss     = ws + 2 * np;                      // np
  int*    bmeta  = (int*)(ws + 3 * np);              // 1024: bcnt|bbase|cursor
  int*    bcnt   = bmeta;
  int*    bbase  = bmeta + 260;
  int*    cursor = bmeta + 600;
  int*    csr    = (int*)(ws + 3 * np + 1024);       // e
  int*    pk     = csr + e;                          // e
  ushort* Asb    = (ushort*)(pk + e);                // n*D bf16
  ushort* Bb     = Asb + (size_t)n * D;              // n*D bf16

  const int g256n = (n + 255) / 256;
  const int ggath = (n + 3) / 4;
  const int gchnk = (e + CHUNK - 1) / CHUNK;
  const int ggemm = (nstrips + 7) / 8;

  // ---- bucketed CSR build ----
  k_bzero<<<1, 256, 0, stream>>>(bcnt, nb);
  k_bhist<<<gchnk, 512, 0, stream>>>(ei + e, bcnt, e, nb);
  k_bscan<<<1, 256, 0, stream>>>(bcnt, bbase, cursor, off, nb, n, e);
  k_bscatter<<<gchnk, 512, 0, stream>>>(ei, cursor, pk, e, nb);
  k_bfinal<<<nb, 1024, 0, stream>>>(bbase, pk, off, dinv, csr, n, nb);

  // ---- layer 0: Asb = (x@W0)*dinv ; Bb = bf16(relu(agg*di + b0)) ----
  k_mgemm_f32<<<ggemm, 512, 0, stream>>>(x, W0, dinv, Asb, n, nstrips);
  k_gather<false><<<ggath, 256, 0, stream>>>(off, csr, dinv, Asb, Bb, b0, nullptr, nullptr, n);

  // ---- layer 1: Asb = (Bb@W1)*dinv ; fused layer-2 GEMV ----
  k_mgemm_bf<<<ggemm, 512, 0, stream>>>(Bb, W1, dinv, Asb, n, nstrips);
  k_gather<true><<<ggath, 256, 0, stream>>>(off, csr, dinv, Asb, nullptr, b1, W2, ss, n);

  // ---- scalar aggregate + sigmoid ----
  k_gather_scalar<<<g256n, 256, 0, stream>>>(off, csr, dinv, ss, b2, out, n);
}

// Round 8
// 295.532 us; speedup vs baseline: 1.2229x; 1.2229x over previous
//
#include <hip/hip_runtime.h>
#include <cstddef>

#define D 128
#define BW_LOG 11
#define BW 2048            // nodes per bucket (NB = ceil(n/BW) <= 256 required)
#define CHUNK 8192         // edges per bscatter/bhist block
#define GP 136             // LDS pitch (ushorts): 272B, 16B-aligned, benign 2-way banks
typedef unsigned int uint;
typedef unsigned short ushort;

typedef __attribute__((ext_vector_type(8))) short bf16x8;
typedef __attribute__((ext_vector_type(4))) float f32x4;

// ---- bf16 helpers (RNE) ----
static __device__ __forceinline__ uint bf16r(float x) {
  uint u = __float_as_uint(x);
  return (u + 0x7fffu + ((u >> 16) & 1u)) >> 16;
}
static __device__ __forceinline__ uint pack2(float a, float b) {
  return bf16r(a) | (bf16r(b) << 16);
}
static __device__ __forceinline__ void acc_bf16x8(const uint4 v, float* a) {
  a[0] += __uint_as_float(v.x << 16);
  a[1] += __uint_as_float(v.x & 0xffff0000u);
  a[2] += __uint_as_float(v.y << 16);
  a[3] += __uint_as_float(v.y & 0xffff0000u);
  a[4] += __uint_as_float(v.z << 16);
  a[5] += __uint_as_float(v.z & 0xffff0000u);
  a[6] += __uint_as_float(v.w << 16);
  a[7] += __uint_as_float(v.w & 0xffff0000u);
}

// ================= bucketed CSR build =================
__global__ void k_bzero(int* __restrict__ bcnt, int nb) {
  int t = threadIdx.x;
  if (t < nb) bcnt[t] = 0;
}

__global__ __launch_bounds__(512)
void k_bhist(const int* __restrict__ dstA, int* __restrict__ bcnt, int e, int nb) {
  __shared__ int h[256];
  int t = threadIdx.x;
  if (t < nb) h[t] = 0;
  __syncthreads();
  int base = blockIdx.x * CHUNK;
  int m = min(CHUNK, e - base);
  for (int i = t; i < m; i += 512) atomicAdd(&h[dstA[base + i] >> BW_LOG], 1);
  __syncthreads();
  if (t < nb && h[t]) atomicAdd(&bcnt[t], h[t]);
}

__global__ void k_bscan(const int* __restrict__ bcnt, int* __restrict__ bbase,
                        int* __restrict__ cursor, int* __restrict__ off,
                        int nb, int n, int e) {
  __shared__ int s[256];
  int t = threadIdx.x;
  int v = (t < nb) ? bcnt[t] : 0;
  s[t] = v;
  __syncthreads();
  for (int d = 1; d < 256; d <<= 1) {
    int x = (t >= d) ? s[t - d] : 0;
    __syncthreads();
    s[t] += x;
    __syncthreads();
  }
  if (t < nb) {
    int b = s[t] - v;
    bbase[t] = b;
    cursor[t] = b;
  }
  if (t == 0) {
    bbase[nb] = e;
    off[n] = e;
  }
}

__global__ __launch_bounds__(512)
void k_bscatter(const int* __restrict__ ei, int* __restrict__ cursor,
                int* __restrict__ pk, int e, int nb) {
  __shared__ int h[256], lbase[256], gpos[256], lcur[256], s2[256];
  __shared__ int staged[CHUNK];
  int t = threadIdx.x;
  if (t < nb) h[t] = 0;
  __syncthreads();
  int base = blockIdx.x * CHUNK;
  int m = min(CHUNK, e - base);
  int sv[16], dv[16];
#pragma unroll
  for (int k = 0; k < 16; ++k) {
    int i = t + k * 512;
    sv[k] = 0; dv[k] = 0;
    if (i < m) {
      sv[k] = ei[base + i];
      dv[k] = ei[e + base + i];
      atomicAdd(&h[dv[k] >> BW_LOG], 1);
    }
  }
  __syncthreads();
  if (t < 256) s2[t] = (t < nb) ? h[t] : 0;
  __syncthreads();
  for (int d = 1; d < 256; d <<= 1) {
    int x = 0;
    if (t < 256 && t >= d) x = s2[t - d];
    __syncthreads();
    if (t < 256) s2[t] += x;
    __syncthreads();
  }
  if (t < nb) {
    lbase[t] = s2[t] - h[t];
    lcur[t] = s2[t] - h[t];
    gpos[t] = h[t] ? atomicAdd(&cursor[t], h[t]) : 0;
  }
  __syncthreads();
#pragma unroll
  for (int k = 0; k < 16; ++k) {
    int i = t + k * 512;
    if (i < m) {
      int b = dv[k] >> BW_LOG;
      int p = atomicAdd(&lcur[b], 1);
      staged[p] = sv[k] | ((dv[k] & (BW - 1)) << 17);
    }
  }
  __syncthreads();
  for (int b = 0; b < nb; ++b) {
    int cnt = h[b], lb = lbase[b], gp = gpos[b];
    for (int i = t; i < cnt; i += 512) pk[gp + i] = staged[lb + i];
  }
}

__global__ __launch_bounds__(1024)
void k_bfinal(const int* __restrict__ bbase, const int* __restrict__ pk,
              int* __restrict__ off, float* __restrict__ dinv,
              int* __restrict__ csr, int n, int nb) {
  __shared__ int sc[BW];
  __shared__ int lcur[BW];
  const int b = blockIdx.x;
  const int t = threadIdx.x;
  const int e0 = bbase[b], e1 = bbase[b + 1];
  const int node0 = b << BW_LOG;
  sc[t] = 0; sc[t + 1024] = 0;
  lcur[t] = 0; lcur[t + 1024] = 0;
  __syncthreads();
  for (int i = e0 + t; i < e1; i += 1024) atomicAdd(&sc[(pk[i] >> 17) & (BW - 1)], 1);
  __syncthreads();
  int c0 = sc[t], c1 = sc[t + 1024];
  for (int d = 1; d < BW; d <<= 1) {
    int v0 = (t >= d) ? sc[t - d] : 0;
    int v1 = (t + 1024 >= d) ? sc[t + 1024 - d] : 0;
    __syncthreads();
    sc[t] += v0; sc[t + 1024] += v1;
    __syncthreads();
  }
  int ex0 = sc[t] - c0, ex1 = sc[t + 1024] - c1;
  int na = node0 + t, nbn = node0 + t + 1024;
  if (na < n)  { off[na]  = e0 + ex0; dinv[na]  = rsqrtf((float)c0 + 1.0f); }
  if (nbn < n) { off[nbn] = e0 + ex1; dinv[nbn] = rsqrtf((float)c1 + 1.0f); }
  __syncthreads();
  sc[t] = ex0; sc[t + 1024] = ex1;
  __syncthreads();
  for (int i = e0 + t; i < e1; i += 1024) {
    int v = pk[i];
    int dl = (v >> 17) & (BW - 1);
    int p = atomicAdd(&lcur[dl], 1);
    csr[e0 + sc[dl] + p] = v & 0x1FFFF;
  }
}

// ================= W pre-split: [W0h|W0l|W1h|W1l], transposed [col][k] bf16 =================
__global__ void k_wsplit(const float* __restrict__ W0, const float* __restrict__ W1,
                         ushort* __restrict__ out) {
  int idx = blockIdx.x * 256 + threadIdx.x;
  if (idx >= 32768) return;
  int lay = idx >> 14;
  int rem = idx & 16383;
  int col = rem >> 7, k = rem & 127;
  const float* W = lay ? W1 : W0;
  float w = W[k * D + col];
  uint hb = bf16r(w);
  float hf = __uint_as_float(hb << 16);
  out[lay * 32768 + rem] = (ushort)hb;
  out[lay * 32768 + 16384 + rem] = (ushort)bf16r(w - hf);
}

// ================= MFMA GEMM: Asb(bf16) = (X@W) * dinv[row] =================
// 256 thr / 4 waves. Wh staged in LDS (34.8KB -> 4 blocks/CU); Wl fragments
// read from global (32KB, L1/L2-hot). Grid-stride over 16-row strips.
// BF16A=false: X f32, split hi/lo in-reg, 3 MFMA terms.
// BF16A=true : X exact bf16, 2 MFMA terms.
template <bool BF16A>
__global__ __launch_bounds__(256)
void k_mgemm(const void* __restrict__ Xv, const ushort* __restrict__ Wht,
             const ushort* __restrict__ Wlt, const float* __restrict__ dinv,
             ushort* __restrict__ Asb, int n, int nstrips) {
  __shared__ __align__(16) ushort Wh[128 * GP];
  const int tid = threadIdx.x;

  // stage Wh: 2048 x 16B chunks, straight copy (no conversion)
  for (int c = tid; c < 2048; c += 256) {
    *(uint4*)(&Wh[(c >> 4) * GP + (c & 15) * 8]) = *(const uint4*)(Wht + c * 8);
  }
  __syncthreads();

  const int wv = tid >> 6;
  const int l = tid & 63;
  const int lr = l & 15;        // A-row / B-col within tile
  const int lk = (l >> 4) * 8;  // k sub-offset

  const float* Xf = (const float*)Xv;
  const ushort* Xb = (const ushort*)Xv;

  for (int strip = blockIdx.x * 4 + wv; strip < nstrips; strip += gridDim.x * 4) {
    const int row0 = strip * 16;
    f32x4 acc[8];
#pragma unroll
    for (int t = 0; t < 8; ++t) acc[t] = (f32x4){0.f, 0.f, 0.f, 0.f};

    const int arow = row0 + lr;
    const bool av = (arow < n);

#pragma unroll
    for (int ks = 0; ks < 4; ++ks) {
      const int k0 = ks * 32 + lk;
      bf16x8 ahv, alv;
      if (BF16A) {
        if (av) {
          ahv = *(const bf16x8*)(Xb + (size_t)arow * D + k0);
        } else {
          union { bf16x8 v; ushort a[8]; } z;
#pragma unroll
          for (int j = 0; j < 8; ++j) z.a[j] = 0;
          ahv = z.v;
        }
      } else {
        float a8[8];
        if (av) {
          const float* ap = Xf + (size_t)arow * D + k0;
          float4 u0 = *(const float4*)(ap);
          float4 u1 = *(const float4*)(ap + 4);
          a8[0] = u0.x; a8[1] = u0.y; a8[2] = u0.z; a8[3] = u0.w;
          a8[4] = u1.x; a8[5] = u1.y; a8[6] = u1.z; a8[7] = u1.w;
        } else {
#pragma unroll
          for (int j = 0; j < 8; ++j) a8[j] = 0.f;
        }
        union { bf16x8 v; ushort a[8]; } ah, al;
#pragma unroll
        for (int j = 0; j < 8; ++j) {
          uint hb = bf16r(a8[j]);
          float hf = __uint_as_float(hb << 16);
          ah.a[j] = (ushort)hb;
          al.a[j] = (ushort)bf16r(a8[j] - hf);
        }
        ahv = ah.v;
        alv = al.v;
      }
#pragma unroll
      for (int nt = 0; nt < 8; ++nt) {
        bf16x8 bh = *(const bf16x8*)(&Wh[(nt * 16 + lr) * GP + k0]);
        bf16x8 bl = *(const bf16x8*)(Wlt + (size_t)(nt * 16 + lr) * D + k0);
        acc[nt] = __builtin_amdgcn_mfma_f32_16x16x32_bf16(ahv, bh, acc[nt], 0, 0, 0);
        if (!BF16A)
          acc[nt] = __builtin_amdgcn_mfma_f32_16x16x32_bf16(alv, bh, acc[nt], 0, 0, 0);
        acc[nt] = __builtin_amdgcn_mfma_f32_16x16x32_bf16(ahv, bl, acc[nt], 0, 0, 0);
      }
    }

    // epilogue: C/D layout col=lane&15, row=(lane>>4)*4+reg
#pragma unroll
    for (int r = 0; r < 4; ++r) {
      int row = row0 + (l >> 4) * 4 + r;
      if (row < n) {
        float di = dinv[row];
#pragma unroll
        for (int nt = 0; nt < 8; ++nt) {
          Asb[(size_t)row * D + nt * 16 + lr] = (ushort)bf16r(acc[nt][r] * di);
        }
      }
    }
  }
}

// ================= gather aggregate =================
// FUSE_DOT=false: Bb = bf16(relu(acc*di + b0))  (feeds layer-1 GEMM directly)
// FUSE_DOT=true : ss = dinv*(relu(acc*di + b1) . W2)
template <bool FUSE_DOT>
__global__ __launch_bounds__(256)
void k_gather(const int* __restrict__ off, const int* __restrict__ csr,
              const float* __restrict__ dinv, const ushort* __restrict__ Asb,
              ushort* __restrict__ Bb, const float* __restrict__ bias,
              const float* __restrict__ W2, float* __restrict__ ss, int n) {
  const int wid = blockIdx.x * 4 + (threadIdx.x >> 6);
  if (wid >= n) return;
  const int lane = threadIdx.x & 63;
  const int q = lane >> 4;
  const int li = lane & 15;
  const int c = li << 3;

  float a[8];
#pragma unroll
  for (int k = 0; k < 8; ++k) a[k] = 0.f;
  if (q == 0) {
    uint4 sv = *(const uint4*)(Asb + (size_t)wid * D + c);
    acc_bf16x8(sv, a);
  }

  const int o0 = off[wid], o1 = off[wid + 1];
  for (int j0 = o0; j0 < o1; j0 += 64) {
    int sj = 0;
    if (j0 + lane < o1) sj = csr[j0 + lane];
    const int m = min(64, o1 - j0);
    const int nst = (m + 3) >> 2;
#pragma unroll 4
    for (int t = 0; t < nst; ++t) {
      int idx = (t << 2) + q;
      int s = __shfl(sj, idx);
      if (idx < m) {
        uint4 v = *(const uint4*)(Asb + (size_t)s * D + c);
        acc_bf16x8(v, a);
      }
    }
  }

#pragma unroll
  for (int k = 0; k < 8; ++k) {
    a[k] += __shfl_xor(a[k], 16);
    a[k] += __shfl_xor(a[k], 32);
  }

  const float di = dinv[wid];
  float4 bb0 = *(const float4*)(bias + c);
  float4 bb1 = *(const float4*)(bias + c + 4);
  float v0 = fmaxf(a[0] * di + bb0.x, 0.f);
  float v1 = fmaxf(a[1] * di + bb0.y, 0.f);
  float v2 = fmaxf(a[2] * di + bb0.z, 0.f);
  float v3 = fmaxf(a[3] * di + bb0.w, 0.f);
  float v4 = fmaxf(a[4] * di + bb1.x, 0.f);
  float v5 = fmaxf(a[5] * di + bb1.y, 0.f);
  float v6 = fmaxf(a[6] * di + bb1.z, 0.f);
  float v7 = fmaxf(a[7] * di + bb1.w, 0.f);

  if (FUSE_DOT) {
    float4 w0 = *(const float4*)(W2 + c);
    float4 w1 = *(const float4*)(W2 + c + 4);
    float p = v0 * w0.x + v1 * w0.y + v2 * w0.z + v3 * w0.w +
              v4 * w1.x + v5 * w1.y + v6 * w1.z + v7 * w1.w;
    p += __shfl_xor(p, 1);
    p += __shfl_xor(p, 2);
    p += __shfl_xor(p, 4);
    p += __shfl_xor(p, 8);
    if (lane == 0) ss[wid] = p * di;
  } else {
    if (lane < 16) {
      uint4 w;
      w.x = pack2(v0, v1);
      w.y = pack2(v2, v3);
      w.z = pack2(v4, v5);
      w.w = pack2(v6, v7);
      *(uint4*)(Bb + (size_t)wid * D + c) = w;
    }
  }
}

// ================= scalar gather + sigmoid =================
__global__ void k_gather_scalar(const int* __restrict__ off, const int* __restrict__ csr,
                                const float* __restrict__ dinv, const float* __restrict__ ss,
                                const float* __restrict__ b2, float* __restrict__ out, int n) {
  int i = blockIdx.x * 256 + threadIdx.x;
  if (i >= n) return;
  float acc = ss[i];
  int j = off[i], o1 = off[i + 1];
  float a0 = 0.f, a1 = 0.f, a2 = 0.f, a3 = 0.f;
  for (; j + 4 <= o1; j += 4) {
    int s0 = csr[j], s1 = csr[j + 1], s2 = csr[j + 2], s3 = csr[j + 3];
    a0 += ss[s0];
    a1 += ss[s1];
    a2 += ss[s2];
    a3 += ss[s3];
  }
  for (; j < o1; ++j) a0 += ss[csr[j]];
  acc += (a0 + a1) + (a2 + a3);
  float v = acc * dinv[i] + b2[0];
  out[i] = 1.f / (1.f + expf(-v));
}

// ================= launch =================
extern "C" void kernel_launch(void* const* d_in, const int* in_sizes, int n_in,
                              void* d_out, int out_size, void* d_ws, size_t ws_size,
                              hipStream_t stream) {
  const float* x  = (const float*)d_in[0];
  const int*   ei = (const int*)d_in[1];   // int64 in source collapses to int32 (JAX x64 off)
  const float* W0 = (const float*)d_in[2];
  const float* b0 = (const float*)d_in[3];
  const float* W1 = (const float*)d_in[4];
  const float* b1 = (const float*)d_in[5];
  const float* W2 = (const float*)d_in[6];
  const float* b2 = (const float*)d_in[7];
  float* out = (float*)d_out;

  const int n = in_sizes[0] / D;
  const int e = in_sizes[1] / 2;
  const int nb = (n + BW - 1) / BW;                 // buckets (n=100000 -> 49)
  const int nstrips = (n + 15) / 16;
  const size_t np = ((size_t)n + 256) / 256 * 256;  // holds n+1, 256-aligned

  float* ws = (float*)d_ws;
  int*    off    = (int*)ws;                         // np
  float*  dinv   = ws + np;                          // np
  float*  ss     = ws + 2 * np;                      // np
  int*    bmeta  = (int*)(ws + 3 * np);              // 1024 floats: bcnt|bbase|cursor
  int*    bcnt   = bmeta;
  int*    bbase  = bmeta + 260;
  int*    cursor = bmeta + 600;
  ushort* wsp    = (ushort*)(ws + 3 * np + 1024);    // 65536 ushorts = 32768 float slots
  int*    csr    = (int*)(ws + 3 * np + 1024 + 32768);  // e  (FIX: was +16384, overlapped W1h/W1l)
  int*    pk     = csr + e;                          // e
  ushort* Asb    = (ushort*)(pk + e);                // n*D bf16
  ushort* Bb     = Asb + (size_t)n * D;              // n*D bf16

  const ushort* W0h = wsp;
  const ushort* W0l = wsp + 16384;
  const ushort* W1h = wsp + 32768;
  const ushort* W1l = wsp + 49152;

  const int g256n = (n + 255) / 256;
  const int ggath = (n + 3) / 4;
  const int gchnk = (e + CHUNK - 1) / CHUNK;
  const int ggemm = (nstrips + 3) / 4 < 1024 ? (nstrips + 3) / 4 : 1024;

  // ---- W pre-split (tiny) + bucketed CSR build ----
  k_wsplit<<<128, 256, 0, stream>>>(W0, W1, (ushort*)wsp);
  k_bzero<<<1, 256, 0, stream>>>(bcnt, nb);
  k_bhist<<<gchnk, 512, 0, stream>>>(ei + e, bcnt, e, nb);
  k_bscan<<<1, 256, 0, stream>>>(bcnt, bbase, cursor, off, nb, n, e);
  k_bscatter<<<gchnk, 512, 0, stream>>>(ei, cursor, pk, e, nb);
  k_bfinal<<<nb, 1024, 0, stream>>>(bbase, pk, off, dinv, csr, n, nb);

  // ---- layer 0: Asb = (x@W0)*dinv ; Bb = bf16(relu(agg*di + b0)) ----
  k_mgemm<false><<<ggemm, 256, 0, stream>>>(x, W0h, W0l, dinv, Asb, n, nstrips);
  k_gather<false><<<ggath, 256, 0, stream>>>(off, csr, dinv, Asb, Bb, b0, nullptr, nullptr, n);

  // ---- layer 1: Asb = (Bb@W1)*dinv ; fused layer-2 GEMV ----
  k_mgemm<true><<<ggemm, 256, 0, stream>>>(Bb, W1h, W1l, dinv, Asb, n, nstrips);
  k_gather<true><<<ggath, 256, 0, stream>>>(off, csr, dinv, Asb, nullptr, b1, W2, ss, n);

  // ---- scalar aggregate + sigmoid ----
  k_gather_scalar<<<g256n, 256, 0, stream>>>(off, csr, dinv, ss, b2, out, n);
}